// Round 6
// baseline (504.693 us; speedup 1.0000x reference)
//
#include <hip/hip_runtime.h>
#include <hip/hip_bf16.h>
#include <math.h>

// Problem constants (fixed by reference)
constexpr int T_ = 16384;
constexpr int D_ = 2048;   // hidden
constexpr int H_ = 1024;   // intermediate
constexpr int E_ = 8;

constexpr int MT256 = T_ / 256 + E_;   // 72 worst-case m-tiles (BM=256)
constexpr int NTN   = 2048 / 256;      // 8 n-tiles (both stages: N = 2048)

typedef __bf16 bf16x8 __attribute__((ext_vector_type(8)));
typedef float  f32x4  __attribute__((ext_vector_type(4)));

__device__ __forceinline__ int imin(int a, int b) { return a < b ? a : b; }

#define SCHED0 __builtin_amdgcn_sched_barrier(0)
#define BARX do { SCHED0; __builtin_amdgcn_s_barrier(); SCHED0; } while (0)
#define VMCNT(n) do { asm volatile("s_waitcnt vmcnt(" #n ")" ::: "memory"); SCHED0; } while (0)

__device__ __forceinline__ bf16x8 cvt8(const float* p) {
    float4 u = *reinterpret_cast<const float4*>(p);
    float4 v = *reinterpret_cast<const float4*>(p + 4);
    bf16x8 r;
    r[0] = (__bf16)u.x; r[1] = (__bf16)u.y; r[2] = (__bf16)u.z; r[3] = (__bf16)u.w;
    r[4] = (__bf16)v.x; r[5] = (__bf16)v.y; r[6] = (__bf16)v.z; r[7] = (__bf16)v.w;
    return r;
}

// ---- K-step panel: 256 rows x 32 bf16 cols (64B/row), row-pair packed into
// 128 super-rows of 128B. byte = sr*128 + (o ^ ((sr&7)<<4)), o = (r&1)*64 + q*16.
// Measured SQ_LDS_BANK_CONFLICT == 0 (rounds 4/5). UNCHANGED from round 5.

__device__ __forceinline__ bf16x8 ldp(const char* panel, int r, int q16) {
    int sr = r >> 1;
    int o = ((r & 1) << 6) + q16;
    int byte = sr * 128 + (o ^ ((sr & 7) << 4));
    return *reinterpret_cast<const bf16x8*>(panel + byte);
}

// stage one panel (16KB) via global_load_lds w=16; LDS dest linear, global src
// pre-permuted with the inverse (involution) of the read swizzle.
// 2 instructions per wave -> vmcnt unit = 2 per panel, 4 per K-step (A+B).
template<int K_>
__device__ __forceinline__ void stage_panel(char* dst, const __bf16* __restrict__ src,
                                            int valid, int tid) {
#pragma unroll
    for (int i = 0; i < 2; ++i) {
        int c = i * 512 + tid;               // 0..1023
        int sr = c >> 3, s = c & 7;
        int o = (s ^ (sr & 7)) << 4;         // 0..112
        int r = sr * 2 + (o >> 6);
        int kb = o & 63;                     // byte offset within the 64B row
        int rc = imin(r, valid - 1);
        const char* gp = reinterpret_cast<const char*>(src)
                       + (size_t)rc * (K_ * 2) + kb;
        __builtin_amdgcn_global_load_lds(
            (const __attribute__((address_space(1))) void*)gp,
            (__attribute__((address_space(3))) void*)(dst + c * 16), 16, 0, 0);
    }
}

// expert lookup for BM=256 tiles
__device__ __forceinline__ bool find_expert256(const int* __restrict__ counts, int mt,
                                               int& e, int& row0, int& valid) {
    int macc = 0, start = 0;
    e = -1;
    for (int i = 0; i < E_; ++i) {
        int c = counts[i];
        int t = (c + 255) >> 8;
        if (e < 0 && mt < macc + t) {
            int lm = mt - macc;
            e = i; row0 = start + lm * 256; valid = imin(256, c - lm * 256);
        }
        macc += t; start += c;
    }
    return e >= 0;
}

// ===================== ring-4 K-step pipelined grouped GEMM =====================
// 256x256 tile, BK=32 K-steps, 8 waves (2M x 4N), per-wave 128x64 (acc[8][4]).
// LDS: ring of 4 slots x (A 16KB + B 16KB) = 128KB.
// Iter j: stage slot j+3 (overwrites slot j-1, retired by iter j-1's exit barrier);
// vmcnt(12) = 3 K-steps in flight (issue->wait distance 3 steps ~ HBM latency);
// barrier; 12 ds_read + 32 MFMA; barrier.  2 barriers / 32 MFMA.
template<int K_, bool FUSE>
__global__ __launch_bounds__(512, 2) void ffn_ring(
        const __bf16* __restrict__ A, const __bf16* __restrict__ Bw,
        const int* __restrict__ counts,
        __bf16* __restrict__ hout, float* __restrict__ fout) {
    constexpr int NJ = K_ / 32;
    __shared__ alignas(16) char sA[4][16384];
    __shared__ alignas(16) char sB[4][16384];

    int tid = threadIdx.x;
    // XCD-bijective chunked mapping, m-fastest: each XCD owns one nt panel.
    int f = (int)blockIdx.x;                  // nwg = MT256*NTN = 576, %8 == 0
    int swz = (f & 7) * (MT256 * NTN / 8) + (f >> 3);
    int mt = swz % MT256, nt = swz / MT256;

    int e, row0, valid;
    if (!find_expert256(counts, mt, e, row0, valid)) return;

    int wid = tid >> 6, lane = tid & 63;
    int wr = wid >> 2, wc = wid & 3;          // 2M x 4N
    int frow = lane & 15, q16 = (lane >> 4) << 4;

    const __bf16* Ab = A  + (size_t)row0 * K_;
    const __bf16* Bb = Bw + (size_t)e * 2048 * K_ + (size_t)(nt * 256) * K_;

    f32x4 acc[8][4] = {};

    // prologue: stage K-steps 0,1,2 into slots 0,1,2 (12 loads/wave in flight)
#pragma unroll
    for (int s = 0; s < 3; ++s) {
        stage_panel<K_>(sA[s], Ab + s * 32, valid, tid);
        stage_panel<K_>(sB[s], Bb + s * 32, 256,   tid);
    }

    for (int j = 0; j < NJ; ++j) {
        int slot = j & 3, st = (j + 3) & 3;
        int jn = imin(j + 3, NJ - 1);         // tail: harmless refetch
        stage_panel<K_>(sA[st], Ab + jn * 32, valid, tid);
        stage_panel<K_>(sB[st], Bb + jn * 32, 256,   tid);
        VMCNT(12);                            // drains exactly K-step j's 4 loads
        BARX;                                 // publish slot j to all waves

        const char* ap = sA[slot];
        const char* bp = sB[slot];
        bf16x8 afr[4], bfr[4];
#pragma unroll
        for (int n = 0; n < 4; ++n) bfr[n] = ldp(bp, wc * 64 + n * 16 + frow, q16);
#pragma unroll
        for (int m = 0; m < 4; ++m) afr[m] = ldp(ap, wr * 128 + m * 16 + frow, q16);
        __builtin_amdgcn_s_setprio(1);
#pragma unroll
        for (int m = 0; m < 4; ++m)
#pragma unroll
            for (int n = 0; n < 4; ++n)
                acc[m][n] = __builtin_amdgcn_mfma_f32_16x16x32_bf16(afr[m], bfr[n], acc[m][n], 0, 0, 0);
        __builtin_amdgcn_s_setprio(0);
#pragma unroll
        for (int m = 0; m < 4; ++m) afr[m] = ldp(ap, wr * 128 + (4 + m) * 16 + frow, q16);
        __builtin_amdgcn_s_setprio(1);
#pragma unroll
        for (int m = 0; m < 4; ++m)
#pragma unroll
            for (int n = 0; n < 4; ++n)
                acc[4 + m][n] = __builtin_amdgcn_mfma_f32_16x16x32_bf16(afr[m], bfr[n], acc[4 + m][n], 0, 0, 0);
        __builtin_amdgcn_s_setprio(0);

        BARX;                                 // retire slot j (stage at j+1 overwrites it)
    }
    asm volatile("s_waitcnt vmcnt(0)" ::: "memory");   // drain tail refetch loads

    // ---- epilogue (unchanged from round 5, verified absmax 0.0117) ----
    int q = lane >> 4;
#pragma unroll
    for (int m = 0; m < 8; ++m)
#pragma unroll
        for (int j = 0; j < 4; ++j) {
            int lrow = wr * 128 + m * 16 + q * 4 + j;
            if (lrow < valid) {
                size_t rg = (size_t)(row0 + lrow);
                if (FUSE) {
                    // wb rows interleaved in 32-row groups (16 w1 + 16 w3):
                    // n even -> w1 (c1), n odd -> w3 (c3), same h column.
#pragma unroll
                    for (int p = 0; p < 2; ++p) {
                        float c1 = acc[m][2 * p][j], c3 = acc[m][2 * p + 1][j];
                        float inner = 0.7978845608028654f * (c1 + 0.044715f * c1 * c1 * c1);
                        float g = 0.5f * c1 * (1.0f + tanhf(inner));
                        int col = (nt * 8 + wc * 2 + p) * 16 + frow;
                        hout[rg * H_ + col] = (__bf16)(g * c3);
                    }
                } else {
#pragma unroll
                    for (int n = 0; n < 4; ++n) {
                        int col = nt * 256 + wc * 64 + n * 16 + frow;
                        fout[rg * D_ + col] = acc[m][n][j];
                    }
                }
            }
        }
}

// ---------------- conversion kernels ----------------
__global__ __launch_bounds__(256) void cvt_f32_bf16(const float* __restrict__ in,
                                                    __bf16* __restrict__ out, int n8) {
    int i = blockIdx.x * blockDim.x + threadIdx.x;
    int stride = gridDim.x * blockDim.x;
    for (; i < n8; i += stride) {
        bf16x8 v = cvt8(in + (size_t)i * 8);
        *reinterpret_cast<bf16x8*>(out + (size_t)i * 8) = v;
    }
}

// wb[e][R][d]: rows interleaved in 32-row groups: 16 w1 rows then 16 w3 rows
__global__ __launch_bounds__(256) void interleave_w1w3(const float* __restrict__ w1,
                                                       const float* __restrict__ w3,
                                                       __bf16* __restrict__ wb) {
    int R = blockIdx.x & 2047, e = blockIdx.x >> 11;
    int g = R >> 5, r5 = R & 31;
    const float* src = (r5 < 16 ? w1 : w3)
                     + ((size_t)e * H_ + g * 16 + (r5 & 15)) * D_;
    __bf16* dst = wb + ((size_t)e * 2048 + R) * D_;
    int d = threadIdx.x * 8;
    *reinterpret_cast<bf16x8*>(dst + d) = cvt8(src + d);
}

extern "C" void kernel_launch(void* const* d_in, const int* in_sizes, int n_in,
                              void* d_out, int out_size, void* d_ws, size_t ws_size,
                              hipStream_t stream) {
    const float* x      = (const float*)d_in[0];
    const float* w1     = (const float*)d_in[1];
    const float* w2     = (const float*)d_in[2];
    const float* w3     = (const float*)d_in[3];
    const int*   counts = (const int*)d_in[4];
    float* out = (float*)d_out;

    const size_t XB  = (size_t)T_ * D_ * 2;           // x bf16         67.1 MB
    const size_t HB  = (size_t)T_ * H_ * 2;           // h bf16         33.6 MB
    const size_t WIB = (size_t)E_ * 2 * H_ * D_ * 2;  // wb interleaved 67.1 MB

    char* ws = (char*)d_ws;
    __bf16* xb   = (__bf16*)(ws);
    __bf16* hbuf = (__bf16*)(ws + XB);
    __bf16* wb   = (__bf16*)(ws + XB + HB);
    __bf16* w2b  = (__bf16*)(ws + XB + HB + WIB);
    (void)ws_size;

    cvt_f32_bf16<<<2048, 256, 0, stream>>>(x,  xb,  T_ * D_ / 8);
    interleave_w1w3<<<E_ * 2048, 256, 0, stream>>>(w1, w3, wb);
    cvt_f32_bf16<<<2048, 256, 0, stream>>>(w2, w2b, E_ * D_ * H_ / 8);

    // stage1: N = 2048 (interleaved w1/w3), K = 2048
    ffn_ring<D_, true ><<<MT256 * NTN, 512, 0, stream>>>(xb, wb, counts, hbuf, nullptr);
    // stage2: N = 2048 (= D), K = 1024
    ffn_ring<H_, false><<<MT256 * NTN, 512, 0, stream>>>(hbuf, w2b, counts, nullptr, out);
}

// Round 7
// 382.037 us; speedup vs baseline: 1.3211x; 1.3211x over previous
//
#include <hip/hip_runtime.h>
#include <hip/hip_bf16.h>
#include <math.h>

// Problem constants (fixed by reference)
constexpr int T_ = 16384;
constexpr int D_ = 2048;   // hidden
constexpr int H_ = 1024;   // intermediate
constexpr int E_ = 8;

constexpr int MT256 = T_ / 256 + E_;   // 72 worst-case m-tiles (BM=256)
constexpr int NTN   = 2048 / 256;      // 8 n-tiles (both stages: N = 2048)

typedef __bf16 bf16x8 __attribute__((ext_vector_type(8)));
typedef float  f32x4  __attribute__((ext_vector_type(4)));

__device__ __forceinline__ int imin(int a, int b) { return a < b ? a : b; }

#define SCHED0 __builtin_amdgcn_sched_barrier(0)
#define BARX do { SCHED0; __builtin_amdgcn_s_barrier(); SCHED0; } while (0)
#define VMCNT(n) do { asm volatile("s_waitcnt vmcnt(" #n ")" ::: "memory"); SCHED0; } while (0)
#define LGKM0 do { asm volatile("s_waitcnt lgkmcnt(0)" ::: "memory"); SCHED0; } while (0)

__device__ __forceinline__ bf16x8 cvt8(const float* p) {
    float4 u = *reinterpret_cast<const float4*>(p);
    float4 v = *reinterpret_cast<const float4*>(p + 4);
    bf16x8 r;
    r[0] = (__bf16)u.x; r[1] = (__bf16)u.y; r[2] = (__bf16)u.z; r[3] = (__bf16)u.w;
    r[4] = (__bf16)v.x; r[5] = (__bf16)v.y; r[6] = (__bf16)v.z; r[7] = (__bf16)v.w;
    return r;
}

// ---- K-half panel: 256 rows x 32 bf16 cols (64B/row), row-pair packed into
// 128 super-rows of 128B. byte = sr*128 + (o ^ ((sr&7)<<4)), o = (r&1)*64 + q*16.
// Measured SQ_LDS_BANK_CONFLICT == 0 (rounds 4/5/6). UNCHANGED.

__device__ __forceinline__ bf16x8 ldp(const char* panel, int r, int q16) {
    int sr = r >> 1;
    int o = ((r & 1) << 6) + q16;
    int byte = sr * 128 + (o ^ ((sr & 7) << 4));
    return *reinterpret_cast<const bf16x8*>(panel + byte);
}

// stage one panel (16KB) via global_load_lds w=16; LDS dest linear, global src
// pre-permuted with the inverse (involution) of the read swizzle.
// 2 instructions per wave -> vmcnt unit = 2 per panel.
template<int K_>
__device__ __forceinline__ void stage_panel(char* dst, const __bf16* __restrict__ src,
                                            int valid, int tid) {
#pragma unroll
    for (int i = 0; i < 2; ++i) {
        int c = i * 512 + tid;               // 0..1023
        int sr = c >> 3, s = c & 7;
        int o = (s ^ (sr & 7)) << 4;         // 0..112
        int r = sr * 2 + (o >> 6);
        int kb = o & 63;                     // byte offset within the 64B row
        int rc = imin(r, valid - 1);
        const char* gp = reinterpret_cast<const char*>(src)
                       + (size_t)rc * (K_ * 2) + kb;
        __builtin_amdgcn_global_load_lds(
            (const __attribute__((address_space(1))) void*)gp,
            (__attribute__((address_space(3))) void*)(dst + c * 16), 16, 0, 0);
    }
}

// expert lookup for BM=256 tiles
__device__ __forceinline__ bool find_expert256(const int* __restrict__ counts, int mt,
                                               int& e, int& row0, int& valid) {
    int macc = 0, start = 0;
    e = -1;
    for (int i = 0; i < E_; ++i) {
        int c = counts[i];
        int t = (c + 255) >> 8;
        if (e < 0 && mt < macc + t) {
            int lm = mt - macc;
            e = i; row0 = start + lm * 256; valid = imin(256, c - lm * 256);
        }
        macc += t; start += c;
    }
    return e >= 0;
}

// ================= 256x256 m201-skeleton 4-phase/K-tile grouped GEMM =================
// 8 waves (2M x 4N), per-wave output 128x64 (acc[8][4]).
// LDS: 2 dbuf x 4 panels (Ak0,Bk0,Ak1,Bk1) x 16KB = 128KB.
// Per phase: {ds_read 4-8 x b128; stage 1 panel (2 glds); BAR; lgkmcnt(0); 16 MFMA; BAR}.
// vmcnt(4) at phases 1 & 3 only (post-stage, pre-barrier): outstanding 8 -> 4;
// the 2 panels read next are published by the following barrier. Never 0 in loop.
template<int K_, bool FUSE>
__global__ __launch_bounds__(512, 2) void ffn_pipe3(
        const __bf16* __restrict__ A, const __bf16* __restrict__ Bw,
        const int* __restrict__ counts,
        __bf16* __restrict__ hout, float* __restrict__ fout) {
    constexpr int NT = K_ / 64;
    __shared__ alignas(16) char sP[2][4][16384];

    int tid = threadIdx.x;
    // XCD-bijective chunked mapping, m-fastest: each XCD owns one nt panel.
    int f = (int)blockIdx.x;                  // nwg = MT256*NTN = 576, %8 == 0
    int swz = (f & 7) * (MT256 * NTN / 8) + (f >> 3);
    int mt = swz % MT256, nt = swz / MT256;

    int e, row0, valid;
    if (!find_expert256(counts, mt, e, row0, valid)) return;

    int wid = tid >> 6, lane = tid & 63;
    int wr = wid >> 2, wc = wid & 3;          // 2M x 4N
    int frow = lane & 15, q16 = (lane >> 4) << 4;

    const __bf16* Ab = A  + (size_t)row0 * K_;
    const __bf16* Bb = Bw + (size_t)e * 2048 * K_ + (size_t)(nt * 256) * K_;

    f32x4 acc[8][4] = {};

    // prologue: stage tile 0's 4 panels; drain A0,B0 (keep A1,B1 in flight)
    stage_panel<K_>(sP[0][0], Ab,      valid, tid);
    stage_panel<K_>(sP[0][1], Bb,      256,   tid);
    stage_panel<K_>(sP[0][2], Ab + 32, valid, tid);
    stage_panel<K_>(sP[0][3], Bb + 32, 256,   tid);
    VMCNT(4);
    BARX;

    for (int tt = 0; tt < NT; tt += 2) {
#pragma unroll
        for (int u = 0; u < 2; ++u) {
            const int c = u, nc = u ^ 1;      // compile-time buffer index
            int t = tt + u;
            int t1 = imin(t + 1, NT - 1);     // tail: harmless refetch
            const __bf16* An = Ab + t1 * 64;
            const __bf16* Bn = Bb + t1 * 64;
            bf16x8 afr[4], bfr[4];

            // ---- phase 0: k-half 0, m-frags 0-3 ----
#pragma unroll
            for (int n = 0; n < 4; ++n) bfr[n] = ldp(sP[c][1], wc * 64 + n * 16 + frow, q16);
#pragma unroll
            for (int m = 0; m < 4; ++m) afr[m] = ldp(sP[c][0], wr * 128 + m * 16 + frow, q16);
            stage_panel<K_>(sP[nc][0], An, valid, tid);
            BARX; LGKM0;
            __builtin_amdgcn_s_setprio(1);
#pragma unroll
            for (int m = 0; m < 4; ++m)
#pragma unroll
                for (int n = 0; n < 4; ++n)
                    acc[m][n] = __builtin_amdgcn_mfma_f32_16x16x32_bf16(afr[m], bfr[n], acc[m][n], 0, 0, 0);
            __builtin_amdgcn_s_setprio(0);
            BARX;

            // ---- phase 1: k-half 0, m-frags 4-7 (bfr reused) ----
#pragma unroll
            for (int m = 0; m < 4; ++m) afr[m] = ldp(sP[c][0], wr * 128 + (4 + m) * 16 + frow, q16);
            stage_panel<K_>(sP[nc][1], Bn, 256, tid);
            VMCNT(4);                          // drains A1(t),B1(t); published by next BAR
            BARX; LGKM0;
            __builtin_amdgcn_s_setprio(1);
#pragma unroll
            for (int m = 0; m < 4; ++m)
#pragma unroll
                for (int n = 0; n < 4; ++n)
                    acc[4 + m][n] = __builtin_amdgcn_mfma_f32_16x16x32_bf16(afr[m], bfr[n], acc[4 + m][n], 0, 0, 0);
            __builtin_amdgcn_s_setprio(0);
            BARX;

            // ---- phase 2: k-half 1, m-frags 0-3 ----
#pragma unroll
            for (int n = 0; n < 4; ++n) bfr[n] = ldp(sP[c][3], wc * 64 + n * 16 + frow, q16);
#pragma unroll
            for (int m = 0; m < 4; ++m) afr[m] = ldp(sP[c][2], wr * 128 + m * 16 + frow, q16);
            stage_panel<K_>(sP[nc][2], An + 32, valid, tid);
            BARX; LGKM0;
            __builtin_amdgcn_s_setprio(1);
#pragma unroll
            for (int m = 0; m < 4; ++m)
#pragma unroll
                for (int n = 0; n < 4; ++n)
                    acc[m][n] = __builtin_amdgcn_mfma_f32_16x16x32_bf16(afr[m], bfr[n], acc[m][n], 0, 0, 0);
            __builtin_amdgcn_s_setprio(0);
            BARX;

            // ---- phase 3: k-half 1, m-frags 4-7 (bfr reused) ----
#pragma unroll
            for (int m = 0; m < 4; ++m) afr[m] = ldp(sP[c][2], wr * 128 + (4 + m) * 16 + frow, q16);
            stage_panel<K_>(sP[nc][3], Bn + 32, 256, tid);
            VMCNT(4);                          // drains A0(t+1),B0(t+1); published by next BAR
            BARX; LGKM0;
            __builtin_amdgcn_s_setprio(1);
#pragma unroll
            for (int m = 0; m < 4; ++m)
#pragma unroll
                for (int n = 0; n < 4; ++n)
                    acc[4 + m][n] = __builtin_amdgcn_mfma_f32_16x16x32_bf16(afr[m], bfr[n], acc[4 + m][n], 0, 0, 0);
            __builtin_amdgcn_s_setprio(0);
            BARX;
        }
    }
    asm volatile("s_waitcnt vmcnt(0)" ::: "memory");   // drain tail refetch loads

    // ---- epilogue (unchanged, verified absmax 0.0117) ----
    int q = lane >> 4;
#pragma unroll
    for (int m = 0; m < 8; ++m)
#pragma unroll
        for (int j = 0; j < 4; ++j) {
            int lrow = wr * 128 + m * 16 + q * 4 + j;
            if (lrow < valid) {
                size_t rg = (size_t)(row0 + lrow);
                if (FUSE) {
                    // wb rows interleaved in 32-row groups (16 w1 + 16 w3):
                    // n even -> w1 (c1), n odd -> w3 (c3), same h column.
#pragma unroll
                    for (int p = 0; p < 2; ++p) {
                        float c1 = acc[m][2 * p][j], c3 = acc[m][2 * p + 1][j];
                        float inner = 0.7978845608028654f * (c1 + 0.044715f * c1 * c1 * c1);
                        float g = 0.5f * c1 * (1.0f + tanhf(inner));
                        int col = (nt * 8 + wc * 2 + p) * 16 + frow;
                        hout[rg * H_ + col] = (__bf16)(g * c3);
                    }
                } else {
#pragma unroll
                    for (int n = 0; n < 4; ++n) {
                        int col = nt * 256 + wc * 64 + n * 16 + frow;
                        fout[rg * D_ + col] = acc[m][n][j];
                    }
                }
            }
        }
}

// ---------------- conversion kernels ----------------
__global__ __launch_bounds__(256) void cvt_f32_bf16(const float* __restrict__ in,
                                                    __bf16* __restrict__ out, int n8) {
    int i = blockIdx.x * blockDim.x + threadIdx.x;
    int stride = gridDim.x * blockDim.x;
    for (; i < n8; i += stride) {
        bf16x8 v = cvt8(in + (size_t)i * 8);
        *reinterpret_cast<bf16x8*>(out + (size_t)i * 8) = v;
    }
}

// wb[e][R][d]: rows interleaved in 32-row groups: 16 w1 rows then 16 w3 rows
__global__ __launch_bounds__(256) void interleave_w1w3(const float* __restrict__ w1,
                                                       const float* __restrict__ w3,
                                                       __bf16* __restrict__ wb) {
    int R = blockIdx.x & 2047, e = blockIdx.x >> 11;
    int g = R >> 5, r5 = R & 31;
    const float* src = (r5 < 16 ? w1 : w3)
                     + ((size_t)e * H_ + g * 16 + (r5 & 15)) * D_;
    __bf16* dst = wb + ((size_t)e * 2048 + R) * D_;
    int d = threadIdx.x * 8;
    *reinterpret_cast<bf16x8*>(dst + d) = cvt8(src + d);
}

extern "C" void kernel_launch(void* const* d_in, const int* in_sizes, int n_in,
                              void* d_out, int out_size, void* d_ws, size_t ws_size,
                              hipStream_t stream) {
    const float* x      = (const float*)d_in[0];
    const float* w1     = (const float*)d_in[1];
    const float* w2     = (const float*)d_in[2];
    const float* w3     = (const float*)d_in[3];
    const int*   counts = (const int*)d_in[4];
    float* out = (float*)d_out;

    const size_t XB  = (size_t)T_ * D_ * 2;           // x bf16         67.1 MB
    const size_t HB  = (size_t)T_ * H_ * 2;           // h bf16         33.6 MB
    const size_t WIB = (size_t)E_ * 2 * H_ * D_ * 2;  // wb interleaved 67.1 MB

    char* ws = (char*)d_ws;
    __bf16* xb   = (__bf16*)(ws);
    __bf16* hbuf = (__bf16*)(ws + XB);
    __bf16* wb   = (__bf16*)(ws + XB + HB);
    __bf16* w2b  = (__bf16*)(ws + XB + HB + WIB);
    (void)ws_size;

    cvt_f32_bf16<<<2048, 256, 0, stream>>>(x,  xb,  T_ * D_ / 8);
    interleave_w1w3<<<E_ * 2048, 256, 0, stream>>>(w1, w3, wb);
    cvt_f32_bf16<<<2048, 256, 0, stream>>>(w2, w2b, E_ * D_ * H_ / 8);

    // stage1: N = 2048 (interleaved w1/w3), K = 2048
    ffn_pipe3<D_, true ><<<MT256 * NTN, 512, 0, stream>>>(xb, wb, counts, hbuf, nullptr);
    // stage2: N = 2048 (= D), K = 1024
    ffn_pipe3<H_, false><<<MT256 * NTN, 512, 0, stream>>>(hbuf, w2b, counts, nullptr, out);
}